// Round 6
// baseline (213.204 us; speedup 1.0000x reference)
//
#include <hip/hip_runtime.h>

typedef _Float16 f16;
typedef f16  f16x8 __attribute__((ext_vector_type(8)));
typedef f16  f16x2 __attribute__((ext_vector_type(2)));
typedef float f32x4 __attribute__((ext_vector_type(4)));

#define W 512
#define H 512
#define NSLICES 48
#define KS 11
#define PITCH 18            // f16 per LDS row (36 B): vconv u16 reads hit 32 distinct banks
#define NW 4                // waves per block
#define NBLK 12288          // 49152 wave-tiles / 4
#define C1_SSIM 0.0001f
#define C2_SSIM 0.0009f
#define NTOTAL 12582912.0f

// Normalized separable Gaussian (ksize=11, sigma=1.5), f32 master copy.
__device__ __constant__ const float GW[KS] = {
    1.02838e-3f, 7.59876e-3f, 3.600076e-2f, 1.0936069e-1f, 2.1300554e-1f,
    2.6601172e-1f,
    2.1300554e-1f, 1.0936069e-1f, 3.600076e-2f, 7.59876e-3f, 1.02838e-3f
};

__device__ inline float ssim_px(float ux, float uy, float uxx, float uyy, float uxy) {
    const float uxuy = ux * uy;
    const float a = 2.f * uxuy + C1_SSIM;
    const float b = 2.f * (uxy - uxuy) + C2_SSIM;
    const float c = ux * ux + uy * uy + C1_SSIM;
    const float d = (uxx - ux * ux) + (uyy - uy * uy) + C2_SSIM;
    return (a * b) * __builtin_amdgcn_rcpf(c * d);
}

// 8 consecutive floats from row ry, cols xs..xs+7, zero-padded outside image.
// 4-byte-aligned vector loads (xs is not 16B-aligned; gfx9 global loads only
// need element alignment).
struct __attribute__((aligned(4))) F4 { float x, y, z, w; };

__device__ __forceinline__ void load8f(const float* __restrict__ base, int ry,
                                       int xs, float v[8]) {
    if ((unsigned)ry < (unsigned)H) {
        const float* r = base + ((size_t)ry << 9);
        if ((unsigned)xs <= (unsigned)(W - 8)) {
            const F4 a = *(const F4*)(r + xs);
            const F4 b = *(const F4*)(r + xs + 4);
            v[0] = a.x; v[1] = a.y; v[2] = a.z; v[3] = a.w;
            v[4] = b.x; v[5] = b.y; v[6] = b.z; v[7] = b.w;
        } else {
            #pragma unroll
            for (int j = 0; j < 8; ++j) {
                const int x = xs + j;
                v[j] = ((unsigned)x < (unsigned)W) ? r[x] : 0.f;
            }
        }
    } else {
        #pragma unroll
        for (int j = 0; j < 8; ++j) v[j] = 0.f;
    }
}

// One wave = one 16x16 output tile. Both convs are banded matmuls with the
// SAME constant A (A[m][k] = G[k-m], zero outside band; zero for k>=26 so
// K=32 tail rows are annihilated). No __syncthreads: per-wave LDS slice only.
// Layouts (m89/m120-verified): A: m=lane&15, k=8*(lane>>4)+j.
//                              B: n=lane&15, k=8*(lane>>4)+j.
//                              D: col=lane&15, row=4*(lane>>4)+reg.
__global__ __launch_bounds__(256)
void ssim_main(const float* __restrict__ simg, const float* __restrict__ timg,
               float* __restrict__ accum) {
    __shared__ f16 hsh[NW][5][32][PITCH];   // 23040 B

    const int tid  = threadIdx.x;
    const int w    = tid >> 6;
    const int lane = tid & 63;
    const int n    = lane & 15;     // A-row m == B-col n == D-col
    const int q    = lane >> 4;

    const int L  = blockIdx.x * NW + w;     // wave-tile id
    const int z  = L >> 10;                 // slice (32x32 tiles each)
    const int r  = L & 1023;
    const int ty = r >> 5;
    const int tx = r & 31;

    const float* sp = simg + ((size_t)z << 18);
    const float* tp = timg + ((size_t)z << 18);
    const int x0 = tx << 4;
    const int y0 = (ty << 4) - 5;           // first h-row needed
    const int xs = x0 - 5 + (q << 3);       // this lane's 8-col x window

    // Constant banded-weight A fragment (f16).
    f16x8 af;
    #pragma unroll
    for (int j = 0; j < 8; ++j) {
        const int k = (q << 3) + j;
        const int d = k - n;
        af[j] = (d >= 0 && d < KS) ? (f16)GW[d] : (f16)0.f;
    }

    // ---- Global -> f16 B-fragments (2 y-halves x {s,t}) ----
    float v[8];
    f16x8 s0, s1, t0, t1;
    load8f(sp, y0 + n,      xs, v);
    #pragma unroll
    for (int j = 0; j < 8; ++j) s0[j] = (f16)v[j];
    load8f(sp, y0 + 16 + n, xs, v);
    #pragma unroll
    for (int j = 0; j < 8; ++j) s1[j] = (f16)v[j];
    load8f(tp, y0 + n,      xs, v);
    #pragma unroll
    for (int j = 0; j < 8; ++j) t0[j] = (f16)v[j];
    load8f(tp, y0 + 16 + n, xs, v);
    #pragma unroll
    for (int j = 0; j < 8; ++j) t1[j] = (f16)v[j];

    // Product channels in-register (v_pk_mul_f16).
    f16x8 b0[5], b1[5];
    b0[0] = s0;      b1[0] = s1;
    b0[1] = t0;      b1[1] = t1;
    b0[2] = s0 * s0; b1[2] = s1 * s1;
    b0[3] = t0 * t0; b1[3] = t1 * t1;
    b0[4] = s0 * t0; b1[4] = s1 * t1;

    // ---- Horizontal conv: 2 MFMAs/channel; D row=x-offset, col=y-offset ----
    // Store h[ch][y][x] to LDS as f16 (2x f16x2 per D-frag half).
    #pragma unroll
    for (int c = 0; c < 5; ++c) {
        const f32x4 zero = {0.f, 0.f, 0.f, 0.f};
        const f32x4 d0 = __builtin_amdgcn_mfma_f32_16x16x32_f16(af, b0[c], zero, 0, 0, 0);
        const f32x4 d1 = __builtin_amdgcn_mfma_f32_16x16x32_f16(af, b1[c], zero, 0, 0, 0);
        f16x2 p;
        p[0] = (f16)d0[0]; p[1] = (f16)d0[1];
        *(f16x2*)&hsh[w][c][n][(q << 2)]          = p;
        p[0] = (f16)d0[2]; p[1] = (f16)d0[3];
        *(f16x2*)&hsh[w][c][n][(q << 2) + 2]      = p;
        p[0] = (f16)d1[0]; p[1] = (f16)d1[1];
        *(f16x2*)&hsh[w][c][16 + n][(q << 2)]     = p;
        p[0] = (f16)d1[2]; p[1] = (f16)d1[3];
        *(f16x2*)&hsh[w][c][16 + n][(q << 2) + 2] = p;
    }

    // ---- Vertical conv: read B'[k=y][n=x] (u16, conflict-free at pitch 36B),
    // one MFMA per channel. D: col=x, row=y-offset. ----
    f32x4 acc[5];
    #pragma unroll
    for (int c = 0; c < 5; ++c) {
        f16x8 bf;
        #pragma unroll
        for (int j = 0; j < 8; ++j)
            bf[j] = hsh[w][c][(q << 3) + j][n];
        const f32x4 zero = {0.f, 0.f, 0.f, 0.f};
        acc[c] = __builtin_amdgcn_mfma_f32_16x16x32_f16(af, bf, zero, 0, 0, 0);
    }

    // ---- SSIM on 4 pixels/lane + wave reduction + one atomic/wave ----
    float sum = 0.f;
    #pragma unroll
    for (int rg = 0; rg < 4; ++rg)
        sum += ssim_px(acc[0][rg], acc[1][rg], acc[2][rg], acc[3][rg], acc[4][rg]);
    #pragma unroll
    for (int off = 32; off > 0; off >>= 1)
        sum += __shfl_down(sum, off, 64);
    if (lane == 0) atomicAdd(&accum[z << 4], sum);
}

__global__ void ssim_final(const float* __restrict__ accum, float* __restrict__ out) {
    float s = 0.f;
    #pragma unroll
    for (int i = 0; i < NSLICES; ++i) s += accum[i * 16];
    out[0] = 1.f - s * (1.f / NTOTAL);
}

extern "C" void kernel_launch(void* const* d_in, const int* in_sizes, int n_in,
                              void* d_out, int out_size, void* d_ws, size_t ws_size,
                              hipStream_t stream) {
    const float* s = (const float*)d_in[0];
    const float* t = (const float*)d_in[1];
    float* out   = (float*)d_out;
    float* accum = (float*)d_ws;

    hipMemsetAsync(accum, 0, NSLICES * 16 * sizeof(float), stream);
    ssim_main<<<dim3(NBLK), 256, 0, stream>>>(s, t, accum);
    ssim_final<<<1, 1, 0, stream>>>(accum, out);
}

// Round 7
// 155.187 us; speedup vs baseline: 1.3739x; 1.3739x over previous
//
#include <hip/hip_runtime.h>

typedef _Float16 f16;
typedef f16  f16x8 __attribute__((ext_vector_type(8)));
typedef f16  f16x2 __attribute__((ext_vector_type(2)));
typedef float f32x4 __attribute__((ext_vector_type(4)));

#define W 512
#define H 512
#define KS 11
#define ROWS 48             // stored hconv rows per wave-tile (3 groups of 16)
#define PITCH 18            // f16 per stored row (36 B)
#define NW 4                // waves per block
#define NBLK 6144           // 24576 wave-tiles (16x32 px each) / 4
#define NLINES 256          // spread accumulator lines (64 B apart)
#define C1_SSIM 0.0001f
#define C2_SSIM 0.0009f
#define NTOTAL 12582912.0f

// Normalized separable Gaussian (ksize=11, sigma=1.5), f32 master copy.
__device__ __constant__ const float GW[KS] = {
    1.02838e-3f, 7.59876e-3f, 3.600076e-2f, 1.0936069e-1f, 2.1300554e-1f,
    2.6601172e-1f,
    2.1300554e-1f, 1.0936069e-1f, 3.600076e-2f, 7.59876e-3f, 1.02838e-3f
};

__device__ inline float ssim_px(float ux, float uy, float uxx, float uyy, float uxy) {
    const float uxuy = ux * uy;
    const float a = 2.f * uxuy + C1_SSIM;
    const float b = 2.f * (uxy - uxuy) + C2_SSIM;
    const float c = ux * ux + uy * uy + C1_SSIM;
    const float d = (uxx - ux * ux) + (uyy - uy * uy) + C2_SSIM;
    return (a * b) * __builtin_amdgcn_rcpf(c * d);
}

// 8 consecutive floats from row ry, cols xs..xs+7, zero-padded outside image.
struct __attribute__((aligned(4))) F4 { float x, y, z, w; };

__device__ __forceinline__ void load8f(const float* __restrict__ base, int ry,
                                       int xs, float v[8]) {
    if ((unsigned)ry < (unsigned)H) {
        const float* r = base + ((size_t)ry << 9);
        if ((unsigned)xs <= (unsigned)(W - 8)) {
            const F4 a = *(const F4*)(r + xs);
            const F4 b = *(const F4*)(r + xs + 4);
            v[0] = a.x; v[1] = a.y; v[2] = a.z; v[3] = a.w;
            v[4] = b.x; v[5] = b.y; v[6] = b.z; v[7] = b.w;
        } else {
            #pragma unroll
            for (int j = 0; j < 8; ++j) {
                const int x = xs + j;
                v[j] = ((unsigned)x < (unsigned)W) ? r[x] : 0.f;
            }
        }
    } else {
        #pragma unroll
        for (int j = 0; j < 8; ++j) v[j] = 0.f;
    }
}

// One wave = one 16(x) x 32(y) output tile (2 stacked 16x16 D-tiles).
// Both convs are banded matmuls with the SAME constant A (A[m][k]=G[k-m]).
// Layouts (m89-verified, R6-validated end-to-end, absmax 0.0):
//   A/B: m|n = lane&15, k = 8*(lane>>4)+j.   D: col=lane&15, row=4*(lane>>4)+reg.
__global__ __launch_bounds__(256)
void ssim_main(const float* __restrict__ simg, const float* __restrict__ timg,
               float* __restrict__ accum) {
    __shared__ f16 hsh[NW][5][ROWS][PITCH];   // 34560 B
    __shared__ float red[NW];

    const int tid  = threadIdx.x;
    const int w    = tid >> 6;
    const int lane = tid & 63;
    const int n    = lane & 15;
    const int q    = lane >> 4;

    const int L  = blockIdx.x * NW + w;   // wave-tile id
    const int z  = L >> 9;                // slice: 32 x-tiles * 16 y-tiles
    const int r  = L & 511;
    const int ty = r >> 5;
    const int tx = r & 31;

    const float* sp = simg + ((size_t)z << 18);
    const float* tp = timg + ((size_t)z << 18);
    const int x0 = tx << 4;
    const int y0 = (ty << 5) - 5;         // first h-row needed (stored idx 0)
    const int xs = x0 - 5 + (q << 3);     // this lane's 8-col x window

    // Constant banded-weight A fragment (f16): A[m][k] = G[k-m] on the band.
    f16x8 af;
    #pragma unroll
    for (int j = 0; j < 8; ++j) {
        const int k = (q << 3) + j;
        const int d = k - n;
        af[j] = (d >= 0 && d < KS) ? (f16)GW[d] : (f16)0.f;
    }

    // ---- Load 3 row-groups x {s,t}; cvt to f16 fragments ----
    f16x8 sf[3], tf[3];
    #pragma unroll
    for (int g = 0; g < 3; ++g) {
        float v[8];
        load8f(sp, y0 + (g << 4) + n, xs, v);
        #pragma unroll
        for (int j = 0; j < 8; ++j) sf[g][j] = (f16)v[j];
        load8f(tp, y0 + (g << 4) + n, xs, v);
        #pragma unroll
        for (int j = 0; j < 8; ++j) tf[g][j] = (f16)v[j];
    }

    // ---- Horizontal conv: 5 ch x 3 groups; D[m=x][n=y] -> LDS f16 [y][x] ----
    #pragma unroll
    for (int g = 0; g < 3; ++g) {
        f16x8 bb[5];
        bb[0] = sf[g];
        bb[1] = tf[g];
        bb[2] = sf[g] * sf[g];
        bb[3] = tf[g] * tf[g];
        bb[4] = sf[g] * tf[g];
        #pragma unroll
        for (int c = 0; c < 5; ++c) {
            const f32x4 zero = {0.f, 0.f, 0.f, 0.f};
            const f32x4 d = __builtin_amdgcn_mfma_f32_16x16x32_f16(af, bb[c], zero, 0, 0, 0);
            f16x2 p;
            p[0] = (f16)d[0]; p[1] = (f16)d[1];
            *(f16x2*)&hsh[w][c][(g << 4) + n][(q << 2)]     = p;
            p[0] = (f16)d[2]; p[1] = (f16)d[3];
            *(f16x2*)&hsh[w][c][(g << 4) + n][(q << 2) + 2] = p;
        }
    }

    // ---- Vertical conv: 2 D-tiles x 5 ch. B[n=x][k] = stored row 16t+k. ----
    f32x4 acc[2][5];
    #pragma unroll
    for (int t = 0; t < 2; ++t) {
        #pragma unroll
        for (int c = 0; c < 5; ++c) {
            f16x8 bf;
            #pragma unroll
            for (int j = 0; j < 8; ++j)
                bf[j] = hsh[w][c][(t << 4) + (q << 3) + j][n];
            const f32x4 zero = {0.f, 0.f, 0.f, 0.f};
            acc[t][c] = __builtin_amdgcn_mfma_f32_16x16x32_f16(af, bf, zero, 0, 0, 0);
        }
    }

    // ---- SSIM on 8 px/lane, wave reduce, block reduce, ONE spread atomic ----
    float sum = 0.f;
    #pragma unroll
    for (int t = 0; t < 2; ++t)
        #pragma unroll
        for (int rg = 0; rg < 4; ++rg)
            sum += ssim_px(acc[t][0][rg], acc[t][1][rg], acc[t][2][rg],
                           acc[t][3][rg], acc[t][4][rg]);
    #pragma unroll
    for (int off = 32; off > 0; off >>= 1)
        sum += __shfl_down(sum, off, 64);
    if (lane == 0) red[w] = sum;
    __syncthreads();
    if (tid == 0) {
        // 6144 atomics spread over 256 lines 64 B apart -> ~24 per line.
        atomicAdd(&accum[(blockIdx.x & (NLINES - 1)) << 4],
                  red[0] + red[1] + red[2] + red[3]);
    }
}

__global__ void ssim_final(const float* __restrict__ accum, float* __restrict__ out) {
    const int lane = threadIdx.x;
    float s = 0.f;
    #pragma unroll
    for (int i = 0; i < NLINES / 64; ++i)
        s += accum[((i << 6) + lane) << 4];
    #pragma unroll
    for (int off = 32; off > 0; off >>= 1)
        s += __shfl_down(s, off, 64);
    if (lane == 0) out[0] = 1.f - s * (1.f / NTOTAL);
}

extern "C" void kernel_launch(void* const* d_in, const int* in_sizes, int n_in,
                              void* d_out, int out_size, void* d_ws, size_t ws_size,
                              hipStream_t stream) {
    const float* s = (const float*)d_in[0];
    const float* t = (const float*)d_in[1];
    float* out   = (float*)d_out;
    float* accum = (float*)d_ws;   // NLINES * 16 floats = 16 KB scratch

    hipMemsetAsync(accum, 0, NLINES * 16 * sizeof(float), stream);
    ssim_main<<<dim3(NBLK), 256, 0, stream>>>(s, t, accum);
    ssim_final<<<1, 64, 0, stream>>>(accum, out);
}

// Round 8
// 151.683 us; speedup vs baseline: 1.4056x; 1.0231x over previous
//
#include <hip/hip_runtime.h>

typedef _Float16 f16;
typedef f16  f16x8 __attribute__((ext_vector_type(8)));
typedef f16  f16x2 __attribute__((ext_vector_type(2)));
typedef float f32x4 __attribute__((ext_vector_type(4)));

#define W 512
#define H 512
#define KS 11
#define NW 4                // waves per block
#define NBLK 6144           // 24576 wave-tiles (16x * 32y px) / 4
#define NLINES 256          // spread accumulator lines (64 B apart)
#define C1_SSIM 0.0001f
#define C2_SSIM 0.0009f
#define NTOTAL 12582912.0f

// Normalized separable Gaussian (ksize=11, sigma=1.5), f32 master copy.
__device__ __constant__ const float GW[KS] = {
    1.02838e-3f, 7.59876e-3f, 3.600076e-2f, 1.0936069e-1f, 2.1300554e-1f,
    2.6601172e-1f,
    2.1300554e-1f, 1.0936069e-1f, 3.600076e-2f, 7.59876e-3f, 1.02838e-3f
};

union B32 { f16x2 h; int i; };

__device__ inline float ssim_px(float ux, float uy, float uxx, float uyy, float uxy) {
    const float uxuy = ux * uy;
    const float a = 2.f * uxuy + C1_SSIM;
    const float b = 2.f * (uxy - uxuy) + C2_SSIM;
    const float c = ux * ux + uy * uy + C1_SSIM;
    const float d = (uxx - ux * ux) + (uyy - uy * uy) + C2_SSIM;
    return (a * b) * __builtin_amdgcn_rcpf(c * d);
}

struct __attribute__((aligned(4))) F4 { float x, y, z, w; };

__device__ __forceinline__ void load8f(const float* __restrict__ base, int ry,
                                       int xs, float v[8]) {
    if ((unsigned)ry < (unsigned)H) {
        const float* r = base + ((size_t)ry << 9);
        if ((unsigned)xs <= (unsigned)(W - 8)) {
            const F4 a = *(const F4*)(r + xs);
            const F4 b = *(const F4*)(r + xs + 4);
            v[0] = a.x; v[1] = a.y; v[2] = a.z; v[3] = a.w;
            v[4] = b.x; v[5] = b.y; v[6] = b.z; v[7] = b.w;
        } else {
            #pragma unroll
            for (int j = 0; j < 8; ++j) {
                const int x = xs + j;
                v[j] = ((unsigned)x < (unsigned)W) ? r[x] : 0.f;
            }
        }
    } else {
        #pragma unroll
        for (int j = 0; j < 8; ++j) v[j] = 0.f;
    }
}

__device__ __forceinline__ f16x8 pack8(const float v[8]) {
    f16x8 r;
    #pragma unroll
    for (int p = 0; p < 4; ++p) {
        const f16x2 h = __builtin_bit_cast(
            f16x2, __builtin_amdgcn_cvt_pkrtz(v[2 * p], v[2 * p + 1]));
        r[2 * p]     = h[0];
        r[2 * p + 1] = h[1];
    }
    return r;
}

// One wave = 16(x) x 32(y) outputs. Both convs = banded matmuls sharing ONE
// constant fragment af (G[k-idx] on the band, zero tail annihilates k>=26).
// hconv: D = mfma(img, af)  -> D[m=y][n=xout]: lane=xout, regs=y (4q+r).
// vconv: D = mfma(af, Hfrag)-> D[m=yout][n=x]: lane=x,   regs=yout.
// Hfrag (lane=x, k=y, 8q+j) is built from hconv D by a fixed lane-bit[4:5]
// permutation (__shfl) + group select — NO LDS round-trip, zero conflicts.
// Layout family m89-verified; R6/R7 validated end-to-end (absmax 0.0).
__global__ __launch_bounds__(256, 5)
void ssim_main(const float* __restrict__ simg, const float* __restrict__ timg,
               float* __restrict__ accum) {
    __shared__ float red[NW];

    const int tid  = threadIdx.x;
    const int w    = tid >> 6;
    const int lane = tid & 63;
    const int n    = lane & 15;
    const int q    = lane >> 4;

    const int L  = blockIdx.x * NW + w;   // wave-tile id
    const int z  = L >> 9;                // slice: 32 x-tiles * 16 y-tiles
    const int r  = L & 511;
    const int ty = r >> 5;
    const int tx = r & 31;

    const float* sp = simg + ((size_t)z << 18);
    const float* tp = timg + ((size_t)z << 18);
    const int x0 = tx << 4;
    const int y0 = (ty << 5) - 5;         // stored row 0 (48 rows: 3 groups)
    const int xs = x0 - 5 + (q << 3);     // this lane's 8-col x window

    // Constant banded-weight fragment: val[j] = G[(8q+j) - n] on the band.
    f16x8 af;
    #pragma unroll
    for (int j = 0; j < 8; ++j) {
        const int k = (q << 3) + j;
        const int d = k - n;
        af[j] = (d >= 0 && d < KS) ? (f16)GW[d] : (f16)0.f;
    }

    // Shuffle sources: dest (q,u) pulls from src quad 2(q&1)+(u>>1), same n.
    const int LA = n | ((q & 1) << 5);
    const int LB = LA | 16;

    // ---- Horizontal conv: 3 row-groups x 5 channels -> packed f16 ph ----
    B32 ph[3][5][2];
    #pragma unroll
    for (int g = 0; g < 3; ++g) {
        float v[8];
        load8f(sp, y0 + (g << 4) + n, xs, v);
        const f16x8 sf = pack8(v);
        load8f(tp, y0 + (g << 4) + n, xs, v);
        const f16x8 tf = pack8(v);
        #pragma unroll
        for (int c = 0; c < 5; ++c) {
            f16x8 ch;
            if      (c == 0) ch = sf;
            else if (c == 1) ch = tf;
            else if (c == 2) ch = sf * sf;
            else if (c == 3) ch = tf * tf;
            else             ch = sf * tf;
            const f32x4 zero = {0.f, 0.f, 0.f, 0.f};
            const f32x4 d = __builtin_amdgcn_mfma_f32_16x16x32_f16(ch, af, zero, 0, 0, 0);
            ph[g][c][0].h = __builtin_bit_cast(f16x2, __builtin_amdgcn_cvt_pkrtz(d[0], d[1]));
            ph[g][c][1].h = __builtin_bit_cast(f16x2, __builtin_amdgcn_cvt_pkrtz(d[2], d[3]));
        }
    }

    // ---- Vertical conv via lane-permute transpose + SSIM ----
    float sum = 0.f;
    #pragma unroll
    for (int t = 0; t < 2; ++t) {
        f32x4 acc[5];
        #pragma unroll
        for (int c = 0; c < 5; ++c) {
            // Group t serves dest quads 0,1; group t+1 serves quads 2,3.
            B32 a0, a1, a2, a3, b0, b1, b2, b3, r0, r1, r2, r3;
            a0.i = __shfl(ph[t][c][0].i,     LA, 64);
            a1.i = __shfl(ph[t][c][1].i,     LA, 64);
            a2.i = __shfl(ph[t][c][0].i,     LB, 64);
            a3.i = __shfl(ph[t][c][1].i,     LB, 64);
            b0.i = __shfl(ph[t + 1][c][0].i, LA, 64);
            b1.i = __shfl(ph[t + 1][c][1].i, LA, 64);
            b2.i = __shfl(ph[t + 1][c][0].i, LB, 64);
            b3.i = __shfl(ph[t + 1][c][1].i, LB, 64);
            const bool lo = (q < 2);
            r0.i = lo ? a0.i : b0.i;
            r1.i = lo ? a1.i : b1.i;
            r2.i = lo ? a2.i : b2.i;
            r3.i = lo ? a3.i : b3.i;
            f16x8 bf;
            bf[0] = r0.h[0]; bf[1] = r0.h[1];
            bf[2] = r1.h[0]; bf[3] = r1.h[1];
            bf[4] = r2.h[0]; bf[5] = r2.h[1];
            bf[6] = r3.h[0]; bf[7] = r3.h[1];
            const f32x4 zero = {0.f, 0.f, 0.f, 0.f};
            acc[c] = __builtin_amdgcn_mfma_f32_16x16x32_f16(af, bf, zero, 0, 0, 0);
        }
        #pragma unroll
        for (int rg = 0; rg < 4; ++rg)
            sum += ssim_px(acc[0][rg], acc[1][rg], acc[2][rg], acc[3][rg], acc[4][rg]);
    }

    // ---- Wave reduce, block reduce, one spread atomic per block ----
    #pragma unroll
    for (int off = 32; off > 0; off >>= 1)
        sum += __shfl_down(sum, off, 64);
    if (lane == 0) red[w] = sum;
    __syncthreads();
    if (tid == 0) {
        atomicAdd(&accum[(blockIdx.x & (NLINES - 1)) << 4],
                  red[0] + red[1] + red[2] + red[3]);
    }
}

__global__ void ssim_final(const float* __restrict__ accum, float* __restrict__ out) {
    const int lane = threadIdx.x;
    float s = 0.f;
    #pragma unroll
    for (int i = 0; i < NLINES / 64; ++i)
        s += accum[((i << 6) + lane) << 4];
    #pragma unroll
    for (int off = 32; off > 0; off >>= 1)
        s += __shfl_down(s, off, 64);
    if (lane == 0) out[0] = 1.f - s * (1.f / NTOTAL);
}

extern "C" void kernel_launch(void* const* d_in, const int* in_sizes, int n_in,
                              void* d_out, int out_size, void* d_ws, size_t ws_size,
                              hipStream_t stream) {
    const float* s = (const float*)d_in[0];
    const float* t = (const float*)d_in[1];
    float* out   = (float*)d_out;
    float* accum = (float*)d_ws;   // NLINES * 16 floats = 16 KB scratch

    hipMemsetAsync(accum, 0, NLINES * 16 * sizeof(float), stream);
    ssim_main<<<dim3(NBLK), 256, 0, stream>>>(s, t, accum);
    ssim_final<<<1, 64, 0, stream>>>(accum, out);
}

// Round 9
// 147.599 us; speedup vs baseline: 1.4445x; 1.0277x over previous
//
#include <hip/hip_runtime.h>

typedef _Float16 f16;
typedef f16  f16x8 __attribute__((ext_vector_type(8)));
typedef f16  f16x2 __attribute__((ext_vector_type(2)));
typedef float f32x4 __attribute__((ext_vector_type(4)));

#define W 512
#define H 512
#define KS 11
#define NW 4                // waves per block
#define NBLK 3072           // 12288 wave-tiles (16x * 64y px) / 4
#define NLINES 256          // spread accumulator lines (64 B apart)
#define C1_SSIM 0.0001f
#define C2_SSIM 0.0009f
#define NTOTAL 12582912.0f

// Normalized separable Gaussian (ksize=11, sigma=1.5), f32 master copy.
__device__ __constant__ const float GW[KS] = {
    1.02838e-3f, 7.59876e-3f, 3.600076e-2f, 1.0936069e-1f, 2.1300554e-1f,
    2.6601172e-1f,
    2.1300554e-1f, 1.0936069e-1f, 3.600076e-2f, 7.59876e-3f, 1.02838e-3f
};

union B32 { f16x2 h; int i; };

__device__ inline float ssim_px(float ux, float uy, float uxx, float uyy, float uxy) {
    const float uxuy = ux * uy;
    const float a = 2.f * uxuy + C1_SSIM;
    const float b = 2.f * (uxy - uxuy) + C2_SSIM;
    const float c = ux * ux + uy * uy + C1_SSIM;
    const float d = (uxx - ux * ux) + (uyy - uy * uy) + C2_SSIM;
    return (a * b) * __builtin_amdgcn_rcpf(c * d);
}

struct __attribute__((aligned(4))) F4 { float x, y, z, w; };

__device__ __forceinline__ void load8f(const float* __restrict__ base, int ry,
                                       int xs, float v[8]) {
    if ((unsigned)ry < (unsigned)H) {
        const float* r = base + ((size_t)ry << 9);
        if ((unsigned)xs <= (unsigned)(W - 8)) {
            const F4 a = *(const F4*)(r + xs);
            const F4 b = *(const F4*)(r + xs + 4);
            v[0] = a.x; v[1] = a.y; v[2] = a.z; v[3] = a.w;
            v[4] = b.x; v[5] = b.y; v[6] = b.z; v[7] = b.w;
        } else {
            #pragma unroll
            for (int j = 0; j < 8; ++j) {
                const int x = xs + j;
                v[j] = ((unsigned)x < (unsigned)W) ? r[x] : 0.f;
            }
        }
    } else {
        #pragma unroll
        for (int j = 0; j < 8; ++j) v[j] = 0.f;
    }
}

__device__ __forceinline__ f16x8 pack8(const float v[8]) {
    f16x8 r;
    #pragma unroll
    for (int p = 0; p < 4; ++p) {
        const f16x2 h = __builtin_bit_cast(
            f16x2, __builtin_amdgcn_cvt_pkrtz(v[2 * p], v[2 * p + 1]));
        r[2 * p]     = h[0];
        r[2 * p + 1] = h[1];
    }
    return r;
}

// One wave = 16(x) x 64(y) outputs: a 5-stage software pipeline over row
// groups g=0..4 (16 image rows each). Per group: global load (prefetched one
// stage ahead) -> hconv MFMA -> pack -> shuffle-transpose (sh, parity
// double-buffered). Each vconv tile t=g-1 consumes sh[t] + sh[t+1].
// Fragment algebra identical to R8 (absmax 0.0): one constant band fragment
// af (A[m][k]=G[k-m]; K=32 tail zeros annihilate), hconv D=mfma(img,af)
// (lane=xout, regs=y), transpose via lane-bit[4:5] bpermute + select, vconv
// D=mfma(af,Hfrag) (lane=x, regs=yout).
__global__ __launch_bounds__(256, 4)
void ssim_main(const float* __restrict__ simg, const float* __restrict__ timg,
               float* __restrict__ accum) {
    __shared__ float red[NW];

    const int tid  = threadIdx.x;
    const int w    = tid >> 6;
    const int lane = tid & 63;
    const int n    = lane & 15;
    const int q    = lane >> 4;

    const int L  = blockIdx.x * NW + w;   // wave-tile id (16x x 64y)
    const int z  = L >> 8;                // slice: 32 x-tiles * 8 y-tiles
    const int r  = L & 255;
    const int ty = r >> 5;
    const int tx = r & 31;

    const float* sp = simg + ((size_t)z << 18);
    const float* tp = timg + ((size_t)z << 18);
    const int x0 = tx << 4;
    const int y0 = (ty << 6) - 5;         // stored row 0 (80 rows: 5 groups)
    const int xs = x0 - 5 + (q << 3);     // this lane's 8-col x window

    // Constant banded-weight fragment: val[j] = G[(8q+j) - n] on the band.
    f16x8 af;
    #pragma unroll
    for (int j = 0; j < 8; ++j) {
        const int k = (q << 3) + j;
        const int d = k - n;
        af[j] = (d >= 0 && d < KS) ? (f16)GW[d] : (f16)0.f;
    }

    // Shuffle-transpose source lanes (pull, bpermute semantics).
    const int LA = n | ((q & 1) << 5);
    const int LB = LA | 16;
    const bool lo = (q < 2);

    float va[2][8], vb[2][8];
    B32 sh[2][5][4];
    float sum = 0.f;

    load8f(sp, y0 + n, xs, va[0]);
    load8f(tp, y0 + n, xs, vb[0]);

    #pragma unroll
    for (int g = 0; g < 5; ++g) {
        const int pb = g & 1;
        // Prefetch next row group while this group computes.
        if (g < 4) {
            load8f(sp, y0 + ((g + 1) << 4) + n, xs, va[pb ^ 1]);
            load8f(tp, y0 + ((g + 1) << 4) + n, xs, vb[pb ^ 1]);
        }
        const f16x8 sf = pack8(va[pb]);
        const f16x8 tf = pack8(vb[pb]);
        #pragma unroll
        for (int c = 0; c < 5; ++c) {
            f16x8 ch;
            if      (c == 0) ch = sf;
            else if (c == 1) ch = tf;
            else if (c == 2) ch = sf * sf;
            else if (c == 3) ch = tf * tf;
            else             ch = sf * tf;
            const f32x4 zero = {0.f, 0.f, 0.f, 0.f};
            const f32x4 d = __builtin_amdgcn_mfma_f32_16x16x32_f16(ch, af, zero, 0, 0, 0);
            B32 p0, p1;
            p0.h = __builtin_bit_cast(f16x2, __builtin_amdgcn_cvt_pkrtz(d[0], d[1]));
            p1.h = __builtin_bit_cast(f16x2, __builtin_amdgcn_cvt_pkrtz(d[2], d[3]));
            sh[pb][c][0].i = __shfl(p0.i, LA, 64);
            sh[pb][c][1].i = __shfl(p1.i, LA, 64);
            sh[pb][c][2].i = __shfl(p0.i, LB, 64);
            sh[pb][c][3].i = __shfl(p1.i, LB, 64);
        }
        if (g >= 1) {
            const int pa = pb ^ 1;        // group t = g-1
            f32x4 acc[5];
            #pragma unroll
            for (int c = 0; c < 5; ++c) {
                B32 r0, r1, r2, r3;
                r0.i = lo ? sh[pa][c][0].i : sh[pb][c][0].i;
                r1.i = lo ? sh[pa][c][1].i : sh[pb][c][1].i;
                r2.i = lo ? sh[pa][c][2].i : sh[pb][c][2].i;
                r3.i = lo ? sh[pa][c][3].i : sh[pb][c][3].i;
                f16x8 bf;
                bf[0] = r0.h[0]; bf[1] = r0.h[1];
                bf[2] = r1.h[0]; bf[3] = r1.h[1];
                bf[4] = r2.h[0]; bf[5] = r2.h[1];
                bf[6] = r3.h[0]; bf[7] = r3.h[1];
                const f32x4 zero = {0.f, 0.f, 0.f, 0.f};
                acc[c] = __builtin_amdgcn_mfma_f32_16x16x32_f16(af, bf, zero, 0, 0, 0);
            }
            #pragma unroll
            for (int rg = 0; rg < 4; ++rg)
                sum += ssim_px(acc[0][rg], acc[1][rg], acc[2][rg],
                               acc[3][rg], acc[4][rg]);
        }
    }

    // ---- Wave reduce, block reduce, one spread atomic per block ----
    #pragma unroll
    for (int off = 32; off > 0; off >>= 1)
        sum += __shfl_down(sum, off, 64);
    if (lane == 0) red[w] = sum;
    __syncthreads();
    if (tid == 0) {
        atomicAdd(&accum[(blockIdx.x & (NLINES - 1)) << 4],
                  red[0] + red[1] + red[2] + red[3]);
    }
}

__global__ void ssim_final(const float* __restrict__ accum, float* __restrict__ out) {
    const int lane = threadIdx.x;
    float s = 0.f;
    #pragma unroll
    for (int i = 0; i < NLINES / 64; ++i)
        s += accum[((i << 6) + lane) << 4];
    #pragma unroll
    for (int off = 32; off > 0; off >>= 1)
        s += __shfl_down(s, off, 64);
    if (lane == 0) out[0] = 1.f - s * (1.f / NTOTAL);
}

extern "C" void kernel_launch(void* const* d_in, const int* in_sizes, int n_in,
                              void* d_out, int out_size, void* d_ws, size_t ws_size,
                              hipStream_t stream) {
    const float* s = (const float*)d_in[0];
    const float* t = (const float*)d_in[1];
    float* out   = (float*)d_out;
    float* accum = (float*)d_ws;   // NLINES * 16 floats = 16 KB scratch

    hipMemsetAsync(accum, 0, NLINES * 16 * sizeof(float), stream);
    ssim_main<<<dim3(NBLK), 256, 0, stream>>>(s, t, accum);
    ssim_final<<<1, 64, 0, stream>>>(accum, out);
}